// Round 8
// baseline (295.318 us; speedup 1.0000x reference)
//
#include <hip/hip_runtime.h>
#include <hip/hip_bf16.h>

typedef __attribute__((ext_vector_type(8))) short bf16x8;
typedef __attribute__((ext_vector_type(4))) short bf16x4;
typedef __attribute__((ext_vector_type(4))) float f32x4;

#define MFMA32(a,b,c) __builtin_amdgcn_mfma_f32_16x16x32_bf16(a,b,c,0,0,0)

#if __has_builtin(__builtin_amdgcn_mfma_f32_16x16x16bf16_1k)
#define MFMA16(a,b,c) __builtin_amdgcn_mfma_f32_16x16x16bf16_1k(a,b,c,0,0,0)
#else
static __device__ __forceinline__ f32x4 mfma16_asm(bf16x4 a, bf16x4 b, f32x4 c){
  asm volatile("v_mfma_f32_16x16x16_bf16 %0, %1, %2, %0" : "+v"(c) : "v"(a), "v"(b));
  return c;
}
#define MFMA16(a,b,c) mfma16_asm(a,b,c)
#endif

#define NEGV -65504.0f

__device__ __forceinline__ unsigned short f2bf(float f){
  union { float f; unsigned u; } x; x.f = f;
  unsigned r = x.u + 0x7fffu + ((x.u >> 16) & 1u);
  return (unsigned short)(r >> 16);
}

__device__ __forceinline__ unsigned cvtpk(float a, float b){
  unsigned r;
  asm volatile("v_cvt_pk_bf16_f32 %0, %1, %2" : "=v"(r) : "v"(a), "v"(b));
  return r;   // a -> low 16, b -> high 16
}

// ---------------- fused fp32 -> bf16 convert for x, W_qkv, W_proj ----------------
__global__ void cvt_all(const float* __restrict__ x, const float* __restrict__ wq,
                        const float* __restrict__ wp, unsigned short* __restrict__ out){
  int i = blockIdx.x * 256 + threadIdx.x;
  const float* src; int j;
  if (i < 1572864)      { src = x;  j = i; }
  else if (i < 2015232) { src = wq; j = i - 1572864; }
  else                  { src = wp; j = i - 2015232; }
  float4 f = ((const float4*)src)[j];
  ushort4 u;
  u.x = f2bf(f.x); u.y = f2bf(f.y); u.z = f2bf(f.z); u.w = f2bf(f.w);
  ((ushort4*)out)[i] = u;
}

// ---------------- mask int32 -> bitmask (1 bit per element) ----------------
__global__ __launch_bounds__(256) void mask_to_bits(const int* __restrict__ m,
                                                    unsigned long long* __restrict__ out){
  int gw = (blockIdx.x * 256 + threadIdx.x) >> 6;
  int lane = threadIdx.x & 63;
#pragma unroll
  for (int stp = 0; stp < 16; ++stp) {
    size_t base = ((size_t)gw * 16 + stp) * 64;
    int v = m[base + lane];
    unsigned long long bb = __ballot(v != 0);
    if (lane == 0) out[base >> 6] = bb;
  }
}

// ---------------- LDS-staged QKV GEMM: X[8192,768] @ W[2304,768]^T + b ----------
__global__ __launch_bounds__(256) void gemm_qkv(
    const unsigned short* __restrict__ X,
    const unsigned short* __restrict__ W,
    const float* __restrict__ bias,
    unsigned short* __restrict__ Qd,
    unsigned short* __restrict__ Kd,
    unsigned short* __restrict__ Vd)
{
  __shared__ unsigned short As[128*40];
  __shared__ unsigned short Bs[128*40];
  const int K = 768;
  int tid = threadIdx.x;
  int bm = blockIdx.x & 63;
  int bn = blockIdx.x >> 6;
  int wave = tid >> 6, lane = tid & 63;
  int lo = lane & 15, g = lane >> 4;
  int wr = (wave >> 1) * 64, wc = (wave & 1) * 64;
  int row0 = bm * 128, col0 = bn * 128;

  int sr = tid >> 1;
  int sc = (tid & 1) * 16;
  const unsigned short* gA = X + (size_t)(row0 + sr) * K + sc;
  const unsigned short* gB = W + (size_t)(col0 + sr) * K + sc;
  unsigned short* sA = &As[sr * 40 + sc];
  unsigned short* sB = &Bs[sr * 40 + sc];

  f32x4 acc[4][4] = {};
  for (int k0 = 0; k0 < K; k0 += 32) {
    bf16x8 a0 = *(const bf16x8*)(gA + k0);
    bf16x8 a1 = *(const bf16x8*)(gA + k0 + 8);
    bf16x8 b0 = *(const bf16x8*)(gB + k0);
    bf16x8 b1 = *(const bf16x8*)(gB + k0 + 8);
    __syncthreads();
    *(bf16x8*)(sA)     = a0;
    *(bf16x8*)(sA + 8) = a1;
    *(bf16x8*)(sB)     = b0;
    *(bf16x8*)(sB + 8) = b1;
    __syncthreads();
    bf16x8 af[4], bf[4];
#pragma unroll
    for (int i = 0; i < 4; ++i) af[i] = *(const bf16x8*)&As[(wr + i*16 + lo)*40 + g*8];
#pragma unroll
    for (int i = 0; i < 4; ++i) bf[i] = *(const bf16x8*)&Bs[(wc + i*16 + lo)*40 + g*8];
#pragma unroll
    for (int mi = 0; mi < 4; ++mi)
#pragma unroll
      for (int ni = 0; ni < 4; ++ni)
        acc[mi][ni] = MFMA32(af[mi], bf[ni], acc[mi][ni]);
  }
  int orow0 = row0 + wr, ocol0 = col0 + wc;
#pragma unroll
  for (int ni = 0; ni < 4; ++ni) {
    int col = ocol0 + ni*16 + lo;
    float bc = bias[col];
    int which = col / 768;
    int rem = col - which * 768;
    int h = rem >> 6, d = rem & 63;
    unsigned short* dst = (which == 0) ? Qd : (which == 1) ? Kd : Vd;
    float scale = (which == 0) ? 0.125f : 1.0f;
#pragma unroll
    for (int mi = 0; mi < 4; ++mi) {
#pragma unroll
      for (int r = 0; r < 4; ++r) {
        int row = orow0 + mi*16 + g*4 + r;
        int bb = row >> 10, n = row & 1023;
        dst[(((size_t)bb*12 + h)*1024 + n)*64 + d] = f2bf((acc[mi][ni][r] + bc) * scale);
      }
    }
  }
}

// ---------------- V transpose: [96][1024][64] -> [96][64][1024] ----------------
__global__ __launch_bounds__(256) void vtrans(const unsigned short* __restrict__ V,
                                              unsigned short* __restrict__ Vt){
  __shared__ unsigned short t[64][72];
  int bh = blockIdx.y;
  int n0 = blockIdx.x * 64;
  int tid = threadIdx.x;
  int nl = tid >> 2;
  int dq = (tid & 3) * 16;
  const unsigned short* src = V + ((size_t)bh*1024 + n0 + nl)*64 + dq;
  bf16x8 a0 = *(const bf16x8*)(src);
  bf16x8 a1 = *(const bf16x8*)(src + 8);
  *(bf16x8*)&t[nl][dq]     = a0;
  *(bf16x8*)&t[nl][dq + 8] = a1;
  __syncthreads();
  int d  = tid >> 2;
  int nq = (tid & 3) * 16;
  union { unsigned short s[16]; bf16x8 v[2]; } pk;
#pragma unroll
  for (int j = 0; j < 16; ++j) pk.s[j] = t[nq + j][d];
  unsigned short* dst = Vt + ((size_t)bh*64 + d)*1024 + n0 + nq;
  *(bf16x8*)(dst)     = pk.v[0];
  *(bf16x8*)(dst + 8) = pk.v[1];
}

// ---------------- fused attention core: 4 waves x 32 q-rows, LDS-shared K/V ----
// grid (8 qblocks, 96); block 256 = 4 waves; each wave owns 2 q-groups of 16.
// Issue order per iter: bias/mask (oldest) | STAGE next | compute | vmcnt(8) bar.
__global__ __launch_bounds__(256, 3) void attn_kernel(
    const unsigned short* __restrict__ Qd,
    const unsigned short* __restrict__ Kd,
    const unsigned short* __restrict__ Vt,     // [96][64][1024]
    const float* __restrict__ bias,            // [12,1024,1024] fp32
    const unsigned* __restrict__ maskbits,     // [8*1024][32] u32 words
    float* __restrict__ out1,                  // [96,1024,1024] fp32
    unsigned short* __restrict__ ctx)          // [8192,768] bf16
{
  __shared__ char lds[32768];
  const int N = 1024, D = 64;
  int y = blockIdx.y;
  int h = y >> 3, bb = y & 7;
  int bh = bb * 12 + h;
  int tid = threadIdx.x;
  int wave = tid >> 6, lane = tid & 63;
  int lo = lane & 15, g = lane >> 4;
  int q0 = blockIdx.x * 128 + wave * 32;
  int qrow0 = q0 + lo, qrow1 = q0 + 16 + lo;

  const size_t qo0 = ((size_t)bh * N + qrow0) * D;
  const size_t qo1 = ((size_t)bh * N + qrow1) * D;
  bf16x8 qf00 = *(const bf16x8*)(Qd + qo0 + g*8);
  bf16x8 qf01 = *(const bf16x8*)(Qd + qo0 + 32 + g*8);
  bf16x8 qf10 = *(const bf16x8*)(Qd + qo1 + g*8);
  bf16x8 qf11 = *(const bf16x8*)(Qd + qo1 + 32 + g*8);

  const float* br0 = bias + ((size_t)h * N + qrow0) * N;
  const float* br1 = bias + ((size_t)h * N + qrow1) * N;
  const unsigned* mr0 = maskbits + ((size_t)bb * N + qrow0) * 32;
  const unsigned* mr1 = maskbits + ((size_t)bb * N + qrow1) * 32;
  float* or0 = out1 + ((size_t)bh * N + qrow0) * N;
  float* or1 = out1 + ((size_t)bh * N + qrow1) * N;

  // staging: thread t fills phys lds byte o=t*16 (+4096 for second call);
  // content = tile[swz(o)] so a read at phys=SWZ(logical) returns tile[logical].
  int o  = tid * 16;
  int sw = o ^ (((o >> 7) & 7) << 4);
  const char* kbase = (const char*)(Kd + (size_t)bh * N * D);
  const char* vbase = (const char*)(Vt + (size_t)bh * D * N);
  const char* ksrc  = kbase + sw;                           // + kv*128 per tile
  const char* vsrc  = vbase + (o >> 7) * 2048 + (sw & 127); // + kv*2 per tile
  int wbase = wave << 10;                                   // wave-uniform LDS base

#define GLL(src, dst) __builtin_amdgcn_global_load_lds( \
      (const __attribute__((address_space(1))) unsigned*)(src), \
      (__attribute__((address_space(3))) unsigned*)(dst), 16, 0, 0)
#define STAGE(buf, kv) do { \
    GLL(ksrc + (size_t)(kv)*128,          lds + (buf)*8192 + wbase); \
    GLL(ksrc + (size_t)(kv)*128 + 4096,   lds + (buf)*8192 + wbase + 4096); \
    GLL(vsrc + (size_t)(kv)*2,            lds + 16384 + (buf)*8192 + wbase); \
    GLL(vsrc + (size_t)(kv)*2 + 65536,    lds + 16384 + (buf)*8192 + wbase + 4096); \
  } while (0)

#define SWZ(lb) ((lb) ^ ((((lb) >> 7) & 7) << 4))

  float m0 = -INFINITY, m1 = -INFINITY, l0 = 0.0f, l1 = 0.0f;
  f32x4 oacc0[4] = {}, oacc1[4] = {};   // O^T: lane q=lo, d = c*16 + g*4 + reg

  STAGE(0, 0);
  __syncthreads();
  int cur = 0;

  for (int it = 0; it < 16; ++it) {
    int kv = it * 64;

    // ---- current-iter mask+bias loads FIRST (older than stage -> their
    //      consumption never drains the stage loads) ----
    uint2 mwa = *(const uint2*)(mr0 + it*2);
    uint2 mwb = *(const uint2*)(mr1 + it*2);
    f32x4 bi0[4], bi1[4];
#pragma unroll
    for (int sub = 0; sub < 4; ++sub) {
      bi0[sub] = *(const f32x4*)(br0 + kv + sub*16 + g*4);
      bi1[sub] = *(const f32x4*)(br1 + kv + sub*16 + g*4);
    }
    __builtin_amdgcn_sched_barrier(0);
    if (it < 15) STAGE(cur ^ 1, kv + 64);
    __builtin_amdgcn_sched_barrier(0);

    // ---- QK^T: shared K-frags serve both q-groups ----
    f32x4 s0[4], s1[4];
    __builtin_amdgcn_s_setprio(1);
#pragma unroll
    for (int sub = 0; sub < 4; ++sub) {
      int lbr = (sub*16 + lo) * 128 + g*16;
      bf16x8 k0 = *(const bf16x8*)(lds + cur*8192 + SWZ(lbr));
      bf16x8 k1 = *(const bf16x8*)(lds + cur*8192 + SWZ(lbr + 64));
      f32x4 t = {}; t = MFMA32(k0, qf00, t); t = MFMA32(k1, qf01, t); s0[sub] = t;
      f32x4 u = {}; u = MFMA32(k0, qf10, u); u = MFMA32(k1, qf11, u); s1[sub] = u;
    }
    __builtin_amdgcn_s_setprio(0);

    // ---- mask (bits) + bias + out1 dump ----
    float sp0[16], sp1[16];
#pragma unroll
    for (int sub = 0; sub < 4; ++sub) {
      unsigned mw0s = (sub < 2) ? mwa.x : mwa.y;
      unsigned mw1s = (sub < 2) ? mwb.x : mwb.y;
      int sh = (sub & 1) * 16 + g * 4;
#pragma unroll
      for (int r = 0; r < 4; ++r) {
        sp0[sub*4+r] = (((mw0s >> (sh + r)) & 1u) ? NEGV : s0[sub][r]) + bi0[sub][r];
        sp1[sub*4+r] = (((mw1s >> (sh + r)) & 1u) ? NEGV : s1[sub][r]) + bi1[sub][r];
      }
      f32x4 ov0, ov1;
      ov0[0]=sp0[sub*4]; ov0[1]=sp0[sub*4+1]; ov0[2]=sp0[sub*4+2]; ov0[3]=sp0[sub*4+3];
      ov1[0]=sp1[sub*4]; ov1[1]=sp1[sub*4+1]; ov1[2]=sp1[sub*4+2]; ov1[3]=sp1[sub*4+3];
      __builtin_nontemporal_store(ov0, (f32x4*)(or0 + kv + sub*16 + g*4));
      __builtin_nontemporal_store(ov1, (f32x4*)(or1 + kv + sub*16 + g*4));
    }

    // ---- deferred-max online softmax (both q-groups) ----
    float lx0 = sp0[0], lx1 = sp1[0];
#pragma unroll
    for (int i = 1; i < 16; ++i) { lx0 = fmaxf(lx0, sp0[i]); lx1 = fmaxf(lx1, sp1[i]); }
    bool ok = (lx0 <= m0 + 8.0f) && (lx1 <= m1 + 8.0f);
    if (!__all(ok)) {
      float t0 = fmaxf(lx0, __shfl_xor(lx0, 16)); t0 = fmaxf(t0, __shfl_xor(t0, 32));
      float t1 = fmaxf(lx1, __shfl_xor(lx1, 16)); t1 = fmaxf(t1, __shfl_xor(t1, 32));
      float n0 = fmaxf(m0, t0), n1 = fmaxf(m1, t1);
      float a0 = __expf(m0 - n0), a1 = __expf(m1 - n1);
      l0 *= a0; l1 *= a1;
#pragma unroll
      for (int c = 0; c < 4; ++c) {
        oacc0[c][0]*=a0; oacc0[c][1]*=a0; oacc0[c][2]*=a0; oacc0[c][3]*=a0;
        oacc1[c][0]*=a1; oacc1[c][1]*=a1; oacc1[c][2]*=a1; oacc1[c][3]*=a1;
      }
      m0 = n0; m1 = n1;
    }
    float ls0 = 0.0f, ls1 = 0.0f;
#pragma unroll
    for (int i = 0; i < 16; ++i) {
      sp0[i] = __expf(sp0[i] - m0); ls0 += sp0[i];
      sp1[i] = __expf(sp1[i] - m1); ls1 += sp1[i];
    }
    l0 += ls0; l1 += ls1;

    union { unsigned u[2]; bf16x4 h; } pk0[4], pk1[4];
#pragma unroll
    for (int ks = 0; ks < 4; ++ks) {
      pk0[ks].u[0] = cvtpk(sp0[ks*4],   sp0[ks*4+1]);
      pk0[ks].u[1] = cvtpk(sp0[ks*4+2], sp0[ks*4+3]);
      pk1[ks].u[0] = cvtpk(sp1[ks*4],   sp1[ks*4+1]);
      pk1[ks].u[1] = cvtpk(sp1[ks*4+2], sp1[ks*4+3]);
    }

    // ---- PV: shared V-frags serve both q-groups ----
    __builtin_amdgcn_s_setprio(1);
#pragma unroll
    for (int ks = 0; ks < 4; ++ks)
#pragma unroll
      for (int c = 0; c < 4; ++c) {
        int lbv = (c*16 + lo) * 128 + ks*32 + g*8;
        bf16x4 vf = *(const bf16x4*)(lds + 16384 + cur*8192 + SWZ(lbv));
        oacc0[c] = MFMA16(vf, pk0[ks].h, oacc0[c]);
        oacc1[c] = MFMA16(vf, pk1[ks].h, oacc1[c]);
      }
    __builtin_amdgcn_s_setprio(0);

    cur ^= 1;
    // counted barrier: 8 newest vmem ops are the NT stores -> let them drift;
    // stage loads (older) are retired, making the buffer switch safe.
    __builtin_amdgcn_sched_barrier(0);
    asm volatile("s_waitcnt vmcnt(8)" ::: "memory");
    __builtin_amdgcn_s_barrier();
  }

  l0 += __shfl_xor(l0, 16); l0 += __shfl_xor(l0, 32);
  l1 += __shfl_xor(l1, 16); l1 += __shfl_xor(l1, 32);
  float inv0 = 1.0f / l0, inv1 = 1.0f / l1;

  size_t crow0 = ((size_t)bb * N + qrow0) * 768 + h * 64;
  size_t crow1 = ((size_t)bb * N + qrow1) * 768 + h * 64;
#pragma unroll
  for (int c = 0; c < 4; ++c) {
    ushort4 u0, u1;
    u0.x = f2bf(oacc0[c][0] * inv0); u0.y = f2bf(oacc0[c][1] * inv0);
    u0.z = f2bf(oacc0[c][2] * inv0); u0.w = f2bf(oacc0[c][3] * inv0);
    u1.x = f2bf(oacc1[c][0] * inv1); u1.y = f2bf(oacc1[c][1] * inv1);
    u1.z = f2bf(oacc1[c][2] * inv1); u1.w = f2bf(oacc1[c][3] * inv1);
    *(ushort4*)(ctx + crow0 + c*16 + g*4) = u0;
    *(ushort4*)(ctx + crow1 + c*16 + g*4) = u1;
  }
#undef STAGE
#undef GLL
#undef SWZ
}

// ---------------- LDS-staged proj GEMM: ctx[8192,768] @ Wp[768,768]^T + b ------
__global__ __launch_bounds__(256) void gemm_proj(
    const unsigned short* __restrict__ X,
    const unsigned short* __restrict__ W,
    const float* __restrict__ bias,
    float* __restrict__ out)
{
  __shared__ unsigned short As[128*40];
  __shared__ unsigned short Bs[128*40];
  const int K = 768;
  int tid = threadIdx.x;
  int bm = blockIdx.x & 63;
  int bn = blockIdx.x >> 6;
  int wave = tid >> 6, lane = tid & 63;
  int lo = lane & 15, g = lane >> 4;
  int wr = (wave >> 1) * 64, wc = (wave & 1) * 64;
  int row0 = bm * 128, col0 = bn * 128;

  int sr = tid >> 1;
  int sc = (tid & 1) * 16;
  const unsigned short* gA = X + (size_t)(row0 + sr) * K + sc;
  const unsigned short* gB = W + (size_t)(col0 + sr) * K + sc;
  unsigned short* sA = &As[sr * 40 + sc];
  unsigned short* sB = &Bs[sr * 40 + sc];

  f32x4 acc[4][4] = {};
  for (int k0 = 0; k0 < K; k0 += 32) {
    bf16x8 a0 = *(const bf16x8*)(gA + k0);
    bf16x8 a1 = *(const bf16x8*)(gA + k0 + 8);
    bf16x8 b0 = *(const bf16x8*)(gB + k0);
    bf16x8 b1 = *(const bf16x8*)(gB + k0 + 8);
    __syncthreads();
    *(bf16x8*)(sA)     = a0;
    *(bf16x8*)(sA + 8) = a1;
    *(bf16x8*)(sB)     = b0;
    *(bf16x8*)(sB + 8) = b1;
    __syncthreads();
    bf16x8 af[4], bf[4];
#pragma unroll
    for (int i = 0; i < 4; ++i) af[i] = *(const bf16x8*)&As[(wr + i*16 + lo)*40 + g*8];
#pragma unroll
    for (int i = 0; i < 4; ++i) bf[i] = *(const bf16x8*)&Bs[(wc + i*16 + lo)*40 + g*8];
#pragma unroll
    for (int mi = 0; mi < 4; ++mi)
#pragma unroll
      for (int ni = 0; ni < 4; ++ni)
        acc[mi][ni] = MFMA32(af[mi], bf[ni], acc[mi][ni]);
  }
  int orow0 = row0 + wr, ocol0 = col0 + wc;
#pragma unroll
  for (int ni = 0; ni < 4; ++ni) {
    int col = ocol0 + ni*16 + lo;
    float bc = bias[col];
#pragma unroll
    for (int mi = 0; mi < 4; ++mi) {
#pragma unroll
      for (int r = 0; r < 4; ++r) {
        int row = orow0 + mi*16 + g*4 + r;
        out[(size_t)row * 768 + col] = acc[mi][ni][r] + bc;
      }
    }
  }
}

extern "C" void kernel_launch(void* const* d_in, const int* in_sizes, int n_in,
                              void* d_out, int out_size, void* d_ws, size_t ws_size,
                              hipStream_t stream) {
  const float* x            = (const float*)d_in[0];
  const float* rel_pos_bias = (const float*)d_in[1];
  const int* mask           = (const int*)d_in[2];
  const float* Wqkv         = (const float*)d_in[3];
  const float* bqkv         = (const float*)d_in[4];
  const float* Wproj        = (const float*)d_in[5];
  const float* bproj        = (const float*)d_in[6];

  float* out0 = (float*)d_out;                         // [8,1024,768]
  float* out1 = out0 + (size_t)8 * 1024 * 768;         // [8,12,1024,1024]

  char* ws = (char*)d_ws;
  unsigned short* xb  = (unsigned short*)(ws);            // dead after gemm_qkv -> Vt
  unsigned short* wqb = (unsigned short*)(ws + 12582912); // dead after gemm_qkv -> maskbits
  unsigned short* wpb = (unsigned short*)(ws + 16121856);
  unsigned short* Qb  = (unsigned short*)(ws + 17301504);
  unsigned short* Kb  = (unsigned short*)(ws + 29884416);
  unsigned short* Vb  = (unsigned short*)(ws + 42467328);
  unsigned short* ctx = (unsigned short*)(ws + 55050240);
  unsigned short* Vtb = xb;
  unsigned long long* mbits = (unsigned long long*)(ws + 12582912);

  cvt_all<<<8448, 256, 0, stream>>>(x, Wqkv, Wproj, xb);

  gemm_qkv<<<1152, 256, 0, stream>>>(xb, wqb, bqkv, Qb, Kb, Vb);

  mask_to_bits<<<2048, 256, 0, stream>>>(mask, mbits);

  vtrans<<<dim3(16, 96), 256, 0, stream>>>(Vb, Vtb);

  attn_kernel<<<dim3(8, 96), 256, 0, stream>>>(Qb, Kb, Vtb, rel_pos_bias,
                                               (const unsigned*)mbits, out1, ctx);

  gemm_proj<<<384, 256, 0, stream>>>(ctx, wpb, bproj, out0);
}

// Round 9
// 247.374 us; speedup vs baseline: 1.1938x; 1.1938x over previous
//
#include <hip/hip_runtime.h>
#include <hip/hip_bf16.h>

typedef __attribute__((ext_vector_type(8))) short bf16x8;
typedef __attribute__((ext_vector_type(4))) short bf16x4;
typedef __attribute__((ext_vector_type(4))) float f32x4;

#define MFMA32(a,b,c) __builtin_amdgcn_mfma_f32_16x16x32_bf16(a,b,c,0,0,0)

#if __has_builtin(__builtin_amdgcn_mfma_f32_16x16x16bf16_1k)
#define MFMA16(a,b,c) __builtin_amdgcn_mfma_f32_16x16x16bf16_1k(a,b,c,0,0,0)
#else
static __device__ __forceinline__ f32x4 mfma16_asm(bf16x4 a, bf16x4 b, f32x4 c){
  asm volatile("v_mfma_f32_16x16x16_bf16 %0, %1, %2, %0" : "+v"(c) : "v"(a), "v"(b));
  return c;
}
#define MFMA16(a,b,c) mfma16_asm(a,b,c)
#endif

#define NEGV -65504.0f

__device__ __forceinline__ unsigned short f2bf(float f){
  union { float f; unsigned u; } x; x.f = f;
  unsigned r = x.u + 0x7fffu + ((x.u >> 16) & 1u);
  return (unsigned short)(r >> 16);
}

__device__ __forceinline__ unsigned cvtpk(float a, float b){
  unsigned r;
  asm volatile("v_cvt_pk_bf16_f32 %0, %1, %2" : "=v"(r) : "v"(a), "v"(b));
  return r;   // a -> low 16, b -> high 16
}

// ------- fused: fp32->bf16 convert (x, W_qkv, W_proj) + mask int32->bits -------
// blocks [0,8448): convert;  blocks [8448,10496): mask ballot
__global__ __launch_bounds__(256) void cvt_mask(
    const float* __restrict__ x, const float* __restrict__ wq,
    const float* __restrict__ wp, unsigned short* __restrict__ out,
    const int* __restrict__ m, unsigned long long* __restrict__ mb){
  int bid = blockIdx.x;
  if (bid < 8448) {
    int i = bid * 256 + threadIdx.x;
    const float* src; int j;
    if (i < 1572864)      { src = x;  j = i; }
    else if (i < 2015232) { src = wq; j = i - 1572864; }
    else                  { src = wp; j = i - 2015232; }
    float4 f = ((const float4*)src)[j];
    ushort4 u;
    u.x = f2bf(f.x); u.y = f2bf(f.y); u.z = f2bf(f.z); u.w = f2bf(f.w);
    ((ushort4*)out)[i] = u;
  } else {
    int gw = ((bid - 8448) * 256 + threadIdx.x) >> 6;   // wave id 0..8191
    int lane = threadIdx.x & 63;
#pragma unroll
    for (int stp = 0; stp < 16; ++stp) {
      size_t base = ((size_t)gw * 16 + stp) * 64;
      int v = m[base + lane];
      unsigned long long bbm = __ballot(v != 0);
      if (lane == 0) mb[base >> 6] = bbm;
    }
  }
}

// ---------------- LDS-staged QKV GEMM: X[8192,768] @ W[2304,768]^T + b ----------
// q scaled 0.125 -> Qd[bh][n][d]; k -> Kd[bh][n][d]; v -> Vt[bh][d][n] (transposed!)
__global__ __launch_bounds__(256) void gemm_qkv(
    const unsigned short* __restrict__ X,
    const unsigned short* __restrict__ W,
    const float* __restrict__ bias,
    unsigned short* __restrict__ Qd,
    unsigned short* __restrict__ Kd,
    unsigned short* __restrict__ Vtd)
{
  __shared__ unsigned short As[128*40];
  __shared__ unsigned short Bs[128*40];
  const int K = 768;
  int tid = threadIdx.x;
  int bm = blockIdx.x & 63;
  int bn = blockIdx.x >> 6;
  int wave = tid >> 6, lane = tid & 63;
  int lo = lane & 15, g = lane >> 4;
  int wr = (wave >> 1) * 64, wc = (wave & 1) * 64;
  int row0 = bm * 128, col0 = bn * 128;

  int sr = tid >> 1;
  int sc = (tid & 1) * 16;
  const unsigned short* gA = X + (size_t)(row0 + sr) * K + sc;
  const unsigned short* gB = W + (size_t)(col0 + sr) * K + sc;
  unsigned short* sA = &As[sr * 40 + sc];
  unsigned short* sB = &Bs[sr * 40 + sc];

  f32x4 acc[4][4] = {};
  for (int k0 = 0; k0 < K; k0 += 32) {
    bf16x8 a0 = *(const bf16x8*)(gA + k0);
    bf16x8 a1 = *(const bf16x8*)(gA + k0 + 8);
    bf16x8 b0 = *(const bf16x8*)(gB + k0);
    bf16x8 b1 = *(const bf16x8*)(gB + k0 + 8);
    __syncthreads();
    *(bf16x8*)(sA)     = a0;
    *(bf16x8*)(sA + 8) = a1;
    *(bf16x8*)(sB)     = b0;
    *(bf16x8*)(sB + 8) = b1;
    __syncthreads();
    bf16x8 af[4], bf[4];
#pragma unroll
    for (int i = 0; i < 4; ++i) af[i] = *(const bf16x8*)&As[(wr + i*16 + lo)*40 + g*8];
#pragma unroll
    for (int i = 0; i < 4; ++i) bf[i] = *(const bf16x8*)&Bs[(wc + i*16 + lo)*40 + g*8];
#pragma unroll
    for (int mi = 0; mi < 4; ++mi)
#pragma unroll
      for (int ni = 0; ni < 4; ++ni)
        acc[mi][ni] = MFMA32(af[mi], bf[ni], acc[mi][ni]);
  }
  int orow0 = row0 + wr, ocol0 = col0 + wc;
#pragma unroll
  for (int ni = 0; ni < 4; ++ni) {
    int col = ocol0 + ni*16 + lo;
    float bc = bias[col];
    int which = col / 768;           // uniform per 16-lane group
    int rem = col - which * 768;
    int h = rem >> 6, d = rem & 63;
    if (which == 2) {
      // V: write transposed Vt[(bb*12+h)][d][n], 4 consecutive n per reg quad
#pragma unroll
      for (int mi = 0; mi < 4; ++mi) {
        int row = orow0 + mi*16 + g*4;
        int bb = row >> 10, n = row & 1023;
        ushort4 u;
        u.x = f2bf(acc[mi][ni][0] + bc);
        u.y = f2bf(acc[mi][ni][1] + bc);
        u.z = f2bf(acc[mi][ni][2] + bc);
        u.w = f2bf(acc[mi][ni][3] + bc);
        *(ushort4*)&Vtd[(((size_t)bb*12 + h)*64 + d)*1024 + n] = u;
      }
    } else {
      unsigned short* dst = (which == 0) ? Qd : Kd;
      float scale = (which == 0) ? 0.125f : 1.0f;
#pragma unroll
      for (int mi = 0; mi < 4; ++mi) {
#pragma unroll
        for (int r = 0; r < 4; ++r) {
          int row = orow0 + mi*16 + g*4 + r;
          int bb = row >> 10, n = row & 1023;
          dst[(((size_t)bb*12 + h)*1024 + n)*64 + d] = f2bf((acc[mi][ni][r] + bc) * scale);
        }
      }
    }
  }
}

// ---------------- fused attention core, 8 waves x 16 q-rows, LDS-shared K/V ----
// grid (8 qblocks, 96); block 512; KVBLK=64 double-buffered via global_load_lds.
// Issue order: bias/mask FIRST (oldest), STAGE second -> consuming bias never
// drains stage; NT stores are the 4 newest at the barrier -> vmcnt(4) is real.
__global__ __launch_bounds__(512, 4) void attn_kernel(
    const unsigned short* __restrict__ Qd,
    const unsigned short* __restrict__ Kd,
    const unsigned short* __restrict__ Vt,     // [96][64][1024]
    const float* __restrict__ bias,            // [12,1024,1024] fp32
    const unsigned* __restrict__ maskbits,     // [8*1024][32] u32 words
    float* __restrict__ out1,                  // [96,1024,1024] fp32
    unsigned short* __restrict__ ctx)          // [8192,768] bf16
{
  __shared__ char lds[32768];
  const int N = 1024, D = 64;
  int y = blockIdx.y;
  int h = y >> 3, bb = y & 7;
  int bh = bb * 12 + h;
  int tid = threadIdx.x;
  int wave = tid >> 6, lane = tid & 63;
  int lo = lane & 15, g = lane >> 4;
  int qrow = blockIdx.x * 128 + wave * 16 + lo;

  const size_t qoff = ((size_t)bh * N + qrow) * D;
  bf16x8 qf0 = *(const bf16x8*)(Qd + qoff + g*8);
  bf16x8 qf1 = *(const bf16x8*)(Qd + qoff + 32 + g*8);

  const float* bias_row = bias + ((size_t)h * N + qrow) * N;
  const unsigned* mrow  = maskbits + ((size_t)bb * N + qrow) * 32;
  float* out_row        = out1 + ((size_t)bh * N + qrow) * N;

  // staging: thread t fills phys lds byte o=t*16; content = tile[swz(o)] so a
  // read at phys=SWZ(logical) returns tile[logical].
  int o  = tid * 16;
  int sw = o ^ (((o >> 7) & 7) << 4);
  const char* kbase = (const char*)(Kd + (size_t)bh * N * D);
  const char* vbase = (const char*)(Vt + (size_t)bh * D * N);
  const char* ksrc  = kbase + sw;                           // + kv*128 per tile
  const char* vsrc  = vbase + (o >> 7) * 2048 + (sw & 127); // + kv*2 per tile
  int wbase = wave << 10;                                   // wave-uniform base

#define STAGE(buf, kv) do { \
    __builtin_amdgcn_global_load_lds( \
      (const __attribute__((address_space(1))) unsigned*)(ksrc + (size_t)(kv)*128), \
      (__attribute__((address_space(3))) unsigned*)(lds + (buf)*8192 + wbase), 16, 0, 0); \
    __builtin_amdgcn_global_load_lds( \
      (const __attribute__((address_space(1))) unsigned*)(vsrc + (size_t)(kv)*2), \
      (__attribute__((address_space(3))) unsigned*)(lds + 16384 + (buf)*8192 + wbase), 16, 0, 0); \
  } while (0)

#define SWZ(lb) ((lb) ^ ((((lb) >> 7) & 7) << 4))

  float m_run = -INFINITY, l_part = 0.0f;
  f32x4 oacc[4] = {};   // O^T: lane holds q=lo, d = c*16 + g*4 + reg

  STAGE(0, 0);
  __syncthreads();      // prologue: full drain
  int cur = 0;

  for (int it = 0; it < 16; ++it) {
    int kv = it * 64;

    // ---- current-iter mask+bias loads FIRST (oldest vmem of this iter) ----
    uint2 mw = *(const uint2*)(mrow + it*2);
    f32x4 bi[4];
#pragma unroll
    for (int sub = 0; sub < 4; ++sub)
      bi[sub] = *(const f32x4*)(bias_row + kv + sub*16 + g*4);
    __builtin_amdgcn_sched_barrier(0);
    // ---- next-tile stage (always; last-iter prefetch lands in ws, unused) ----
    STAGE(cur ^ 1, kv + 64);
    __builtin_amdgcn_sched_barrier(0);

    // ---- QK^T: s[sub][r] = S[q=lo][kv + sub*16 + g*4 + r] ----
    f32x4 s[4];
    __builtin_amdgcn_s_setprio(1);
#pragma unroll
    for (int sub = 0; sub < 4; ++sub) {
      int lbr = (sub*16 + lo) * 128 + g*16;
      bf16x8 k0 = *(const bf16x8*)(lds + cur*8192 + SWZ(lbr));
      bf16x8 k1 = *(const bf16x8*)(lds + cur*8192 + SWZ(lbr + 64));
      f32x4 t = {};
      t = MFMA32(k0, qf0, t);
      t = MFMA32(k1, qf1, t);
      s[sub] = t;
    }
    __builtin_amdgcn_s_setprio(0);

    // ---- mask (bits) + bias + out1 dump ----
    float sp[16];
#pragma unroll
    for (int sub = 0; sub < 4; ++sub) {
      unsigned mws = (sub < 2) ? mw.x : mw.y;
      int sh = (sub & 1) * 16 + g * 4;
#pragma unroll
      for (int r = 0; r < 4; ++r)
        sp[sub*4+r] = (((mws >> (sh + r)) & 1u) ? NEGV : s[sub][r]) + bi[sub][r];
      f32x4 ov;
      ov[0] = sp[sub*4]; ov[1] = sp[sub*4+1]; ov[2] = sp[sub*4+2]; ov[3] = sp[sub*4+3];
      __builtin_nontemporal_store(ov, (f32x4*)(out_row + kv + sub*16 + g*4));
    }

    // ---- deferred-max online softmax ----
    float lmax = sp[0];
#pragma unroll
    for (int i = 1; i < 16; ++i) lmax = fmaxf(lmax, sp[i]);
    if (!__all(lmax <= m_run + 8.0f)) {
      float tmax = fmaxf(lmax, __shfl_xor(lmax, 16));
      tmax = fmaxf(tmax, __shfl_xor(tmax, 32));
      float mnew = fmaxf(m_run, tmax);
      float alpha = __expf(m_run - mnew);
      l_part *= alpha;
#pragma unroll
      for (int c = 0; c < 4; ++c) {
        oacc[c][0] *= alpha; oacc[c][1] *= alpha;
        oacc[c][2] *= alpha; oacc[c][3] *= alpha;
      }
      m_run = mnew;
    }
    float lsum = 0.0f;
#pragma unroll
    for (int i = 0; i < 16; ++i) { sp[i] = __expf(sp[i] - m_run); lsum += sp[i]; }
    l_part += lsum;

    union { unsigned u[2]; bf16x4 hh; } pk[4];
#pragma unroll
    for (int ks = 0; ks < 4; ++ks) {
      pk[ks].u[0] = cvtpk(sp[ks*4],   sp[ks*4+1]);
      pk[ks].u[1] = cvtpk(sp[ks*4+2], sp[ks*4+3]);
    }

    // ---- PV: oacc[c] += Vs[d=c*16+lo][k=ks*16+g*4+e] x P ----
    __builtin_amdgcn_s_setprio(1);
#pragma unroll
    for (int ks = 0; ks < 4; ++ks)
#pragma unroll
      for (int c = 0; c < 4; ++c) {
        int lbv = (c*16 + lo) * 128 + ks*32 + g*8;
        bf16x4 vf = *(const bf16x4*)(lds + 16384 + cur*8192 + SWZ(lbv));
        oacc[c] = MFMA16(vf, pk[ks].hh, oacc[c]);
      }
    __builtin_amdgcn_s_setprio(0);

    cur ^= 1;
    // counted barrier: the 4 newest vmem ops are the NT stores -> drift;
    // stage loads (older) are retired -> buffer switch safe.
    __builtin_amdgcn_sched_barrier(0);
    asm volatile("s_waitcnt vmcnt(4)" ::: "memory");
    __builtin_amdgcn_s_barrier();
  }

  l_part += __shfl_xor(l_part, 16);
  l_part += __shfl_xor(l_part, 32);
  float inv = 1.0f / l_part;

  size_t crow = ((size_t)bb * N + qrow) * 768 + h * 64;
#pragma unroll
  for (int c = 0; c < 4; ++c) {
    ushort4 u;
    u.x = f2bf(oacc[c][0] * inv);
    u.y = f2bf(oacc[c][1] * inv);
    u.z = f2bf(oacc[c][2] * inv);
    u.w = f2bf(oacc[c][3] * inv);
    *(ushort4*)(ctx + crow + c*16 + g*4) = u;
  }
#undef STAGE
#undef SWZ
}

// ---------------- LDS-staged proj GEMM: ctx[8192,768] @ Wp[768,768]^T + b ------
__global__ __launch_bounds__(256) void gemm_proj(
    const unsigned short* __restrict__ X,
    const unsigned short* __restrict__ W,
    const float* __restrict__ bias,
    float* __restrict__ out)
{
  __shared__ unsigned short As[128*40];
  __shared__ unsigned short Bs[128*40];
  const int K = 768;
  int tid = threadIdx.x;
  int bm = blockIdx.x & 63;
  int bn = blockIdx.x >> 6;
  int wave = tid >> 6, lane = tid & 63;
  int lo = lane & 15, g = lane >> 4;
  int wr = (wave >> 1) * 64, wc = (wave & 1) * 64;
  int row0 = bm * 128, col0 = bn * 128;

  int sr = tid >> 1;
  int sc = (tid & 1) * 16;
  const unsigned short* gA = X + (size_t)(row0 + sr) * K + sc;
  const unsigned short* gB = W + (size_t)(col0 + sr) * K + sc;
  unsigned short* sA = &As[sr * 40 + sc];
  unsigned short* sB = &Bs[sr * 40 + sc];

  f32x4 acc[4][4] = {};
  for (int k0 = 0; k0 < K; k0 += 32) {
    bf16x8 a0 = *(const bf16x8*)(gA + k0);
    bf16x8 a1 = *(const bf16x8*)(gA + k0 + 8);
    bf16x8 b0 = *(const bf16x8*)(gB + k0);
    bf16x8 b1 = *(const bf16x8*)(gB + k0 + 8);
    __syncthreads();
    *(bf16x8*)(sA)     = a0;
    *(bf16x8*)(sA + 8) = a1;
    *(bf16x8*)(sB)     = b0;
    *(bf16x8*)(sB + 8) = b1;
    __syncthreads();
    bf16x8 af[4], bf[4];
#pragma unroll
    for (int i = 0; i < 4; ++i) af[i] = *(const bf16x8*)&As[(wr + i*16 + lo)*40 + g*8];
#pragma unroll
    for (int i = 0; i < 4; ++i) bf[i] = *(const bf16x8*)&Bs[(wc + i*16 + lo)*40 + g*8];
#pragma unroll
    for (int mi = 0; mi < 4; ++mi)
#pragma unroll
      for (int ni = 0; ni < 4; ++ni)
        acc[mi][ni] = MFMA32(af[mi], bf[ni], acc[mi][ni]);
  }
  int orow0 = row0 + wr, ocol0 = col0 + wc;
#pragma unroll
  for (int ni = 0; ni < 4; ++ni) {
    int col = ocol0 + ni*16 + lo;
    float bc = bias[col];
#pragma unroll
    for (int mi = 0; mi < 4; ++mi) {
#pragma unroll
      for (int r = 0; r < 4; ++r) {
        int row = orow0 + mi*16 + g*4 + r;
        out[(size_t)row * 768 + col] = acc[mi][ni][r] + bc;
      }
    }
  }
}

extern "C" void kernel_launch(void* const* d_in, const int* in_sizes, int n_in,
                              void* d_out, int out_size, void* d_ws, size_t ws_size,
                              hipStream_t stream) {
  const float* x            = (const float*)d_in[0];
  const float* rel_pos_bias = (const float*)d_in[1];
  const int* mask           = (const int*)d_in[2];
  const float* Wqkv         = (const float*)d_in[3];
  const float* bqkv         = (const float*)d_in[4];
  const float* Wproj        = (const float*)d_in[5];
  const float* bproj        = (const float*)d_in[6];

  float* out0 = (float*)d_out;                         // [8,1024,768]
  float* out1 = out0 + (size_t)8 * 1024 * 768;         // [8,12,1024,1024]

  char* ws = (char*)d_ws;
  unsigned short* xb  = (unsigned short*)(ws);            // bf16 x (read-only in gemm_qkv)
  unsigned short* wqb = (unsigned short*)(ws + 12582912);
  unsigned short* wpb = (unsigned short*)(ws + 16121856);
  unsigned short* Qb  = (unsigned short*)(ws + 17301504);
  unsigned short* Kb  = (unsigned short*)(ws + 29884416);
  unsigned short* Vtb = (unsigned short*)(ws + 42467328); // V^T written directly by gemm_qkv
  unsigned short* ctx = (unsigned short*)(ws + 55050240);
  unsigned long long* mbits = (unsigned long long*)(ws + 67633152); // 1 MB

  cvt_mask<<<10496, 256, 0, stream>>>(x, Wqkv, Wproj, xb, mask, mbits);

  gemm_qkv<<<1152, 256, 0, stream>>>(xb, wqb, bqkv, Qb, Kb, Vtb);

  attn_kernel<<<dim3(8, 96), 512, 0, stream>>>(Qb, Kb, Vtb, rel_pos_bias,
                                               (const unsigned*)mbits, out1, ctx);

  gemm_proj<<<384, 256, 0, stream>>>(ctx, wpb, bproj, out0);
}